// Round 7
// baseline (150.087 us; speedup 1.0000x reference)
//
#include <hip/hip_runtime.h>
#include <hip/hip_bf16.h>
#include <cstdint>

// Problem constants
#define NPTS  131072
#define NRET  65536
#define NBAT  64
#define NBUCK (1 << 18)   // buckets = top-18 bits of descending key
#define BSH   14          // d >> 14 -> bucket

// Monotone map f32 -> u32 such that ascending u32 == DESCENDING float value.
__device__ __forceinline__ unsigned int desc_key(float w) {
    unsigned int b = __float_as_uint(w);
    unsigned int s = b ^ ((unsigned int)((int)b >> 31) | 0x80000000u); // ascending
    return ~s;                                                        // descending
}

// Fused: zero 2 MiB (hist+cnt) with all 512 blocks; blocks 0..255 also do the
// per-block partial max of w (exact, order-independent).
__global__ void k_zero_pmax(const float* __restrict__ w, uint4* __restrict__ zp,
                            float* __restrict__ pmax) {
    int j = blockIdx.x, tid = threadIdx.x;
    zp[j * 256 + tid] = make_uint4(0u, 0u, 0u, 0u);
    if (j < 256) {
        __shared__ float sm[256];
        int i = j * 256 + tid;
        float m = fmaxf(w[i], w[i + 65536]);       // NPTS = 2*65536
        sm[tid] = m; __syncthreads();
        for (int off = 128; off > 0; off >>= 1) {
            if (tid < off) sm[tid] = fmaxf(sm[tid], sm[tid + off]);
            __syncthreads();
        }
        if (tid == 0) pmax[j] = sm[0];
    }
}

// e_i = correctly-rounded f32 exp(f32(w_i - m)) via double. One thread per
// numpy 8-accumulator LANE of each 128-elem base block; 8 lanes combined
// pairwise in numpy's order via LDS. Final max over pmax[256] done in-block.
// 32 blocks x 256 threads = 8192 tasks = 1024 base blocks x 8 lanes.
__global__ void k_exp_sum(const float* __restrict__ w, const float* __restrict__ pmax,
                          float* __restrict__ e_out, float* __restrict__ bs) {
    __shared__ float smm[256];
    __shared__ float smr[256];
    int tid = threadIdx.x;
    smm[tid] = pmax[tid]; __syncthreads();
    for (int off = 128; off > 0; off >>= 1) {
        if (tid < off) smm[tid] = fmaxf(smm[tid], smm[tid + off]);
        __syncthreads();
    }
    float m = smm[0];
    int task = blockIdx.x * 256 + tid;       // 0..8191
    int base = task >> 3;                    // base block 0..1023
    int k    = task & 7;                     // accumulator lane
    const float* wp = w + (size_t)base * 128;
    float* ep = e_out + (size_t)base * 128;
    float r = 0.0f;
    #pragma unroll
    for (int i = 0; i < 128; i += 8) {       // numpy order within lane
        float e = (float)exp((double)(wp[i + k] - m));
        ep[i + k] = e;
        r += e;
    }
    smr[tid] = r; __syncthreads();
    if (k == 0)                               // numpy pairwise combine of 8 lanes
        bs[base] = ((smr[tid]+smr[tid+1])+(smr[tid+2]+smr[tid+3]))
                 + ((smr[tid+4]+smr[tid+5])+(smr[tid+6]+smr[tid+7]));
}

// Perfect binary combine tree over 1024 base sums (numpy's recursion shape).
__global__ void k_tree(const float* __restrict__ bs, float* __restrict__ dst) {
    __shared__ float sm[1024];
    int tid = threadIdx.x;
    sm[tid] = bs[tid]; __syncthreads();
    for (int n = 512; n >= 1; n >>= 1) {
        float v = 0.0f;
        if (tid < n) v = sm[2*tid] + sm[2*tid+1];
        __syncthreads();
        if (tid < n) sm[tid] = v;
        __syncthreads();
    }
    if (tid == 0) dst[0] = sm[0];
}

// p_i = e_i / Z (IEEE f32 div, matches np); histogram; numpy base-128 sum of p.
__global__ void k_prob_hist_sum(float* __restrict__ probs, const float* __restrict__ scal,
                                unsigned int* __restrict__ hist, float* __restrict__ bs2) {
    __shared__ float smr[256];
    int tid = threadIdx.x;
    int task = blockIdx.x * 256 + tid;
    int base = task >> 3;
    int k    = task & 7;
    float* pp = probs + (size_t)base * 128;
    float Z = scal[1];
    float r = 0.0f;
    #pragma unroll
    for (int i = 0; i < 128; i += 8) {
        float pv = pp[i + k] / Z;
        pp[i + k] = pv;
        r += pv;
        atomicAdd(&hist[desc_key(pv) >> BSH], 1u);
    }
    smr[tid] = r; __syncthreads();
    if (k == 0)
        bs2[base] = ((smr[tid]+smr[tid+1])+(smr[tid+2]+smr[tid+3]))
                  + ((smr[tid+4]+smr[tid+5])+(smr[tid+6]+smr[tid+7]));
}

// ---------- bucket ranking sort ----------
// 256 blocks x 256 threads; each thread owns 4 consecutive buckets (uint4).
__global__ void k_scan_local(const unsigned int* __restrict__ hist,
                             unsigned int* __restrict__ local,
                             unsigned int* __restrict__ chunksum) {
    __shared__ unsigned int sm[256];
    int tid = threadIdx.x;
    int g0 = (blockIdx.x * 256 + tid) * 4;
    uint4 h = *(const uint4*)&hist[g0];
    unsigned int s = h.x + h.y + h.z + h.w;
    sm[tid] = s; __syncthreads();
    for (int off = 1; off < 256; off <<= 1) {
        unsigned int t = (tid >= off) ? sm[tid - off] : 0u;
        __syncthreads();
        sm[tid] += t;
        __syncthreads();
    }
    unsigned int excl = sm[tid] - s;
    uint4 o;
    o.x = excl; o.y = excl + h.x; o.z = o.y + h.y; o.w = o.z + h.z;
    *(uint4*)&local[g0] = o;
    if (tid == 255) chunksum[blockIdx.x] = sm[255];
}

// Fused: exclusive scan of 256 chunk sums + numpy tree over bs2 -> scal[2].
// Thread tid's 4-leaf sub-sum uses numpy's pairing; LDS tree over 256 partials
// completes the same perfect binary tree as the 1024-leaf recursion.
__global__ void k_scan_chunk_inv(const unsigned int* __restrict__ chunksum,
                                 unsigned int* __restrict__ chunkoff,
                                 const float* __restrict__ bs2,
                                 float* __restrict__ inv_dst) {
    __shared__ unsigned int sm[256];
    __shared__ float smf[256];
    int tid = threadIdx.x;
    unsigned int v = chunksum[tid];
    sm[tid] = v;
    const float* b4 = bs2 + tid * 4;
    smf[tid] = (b4[0] + b4[1]) + (b4[2] + b4[3]);
    __syncthreads();
    for (int off = 1; off < 256; off <<= 1) {
        unsigned int t = (tid >= off) ? sm[tid - off] : 0u;
        __syncthreads();
        sm[tid] += t;
        __syncthreads();
    }
    chunkoff[tid] = sm[tid] - v;
    for (int n = 128; n >= 1; n >>= 1) {
        float t = 0.0f;
        if (tid < n) t = smf[2*tid] + smf[2*tid+1];
        __syncthreads();
        if (tid < n) smf[tid] = t;
        __syncthreads();
    }
    if (tid == 0) inv_dst[0] = 1.0f / (smf[0] + 1e-6f);
}

// Scatter unique key (desc_prob_bits<<17)|idx into its bucket segment.
__global__ void k_scatter(const float* __restrict__ probs,
                          const unsigned int* __restrict__ local,
                          const unsigned int* __restrict__ chunkoff,
                          unsigned int* __restrict__ cnt,
                          unsigned long long* __restrict__ bucketed) {
    int i = blockIdx.x * 256 + threadIdx.x;
    unsigned int d = desc_key(probs[i]);
    unsigned int b = d >> BSH;
    unsigned int base = chunkoff[b >> 10] + local[b];
    unsigned int off = atomicAdd(&cnt[b], 1u);
    bucketed[base + off] = ((unsigned long long)d << 17) | (unsigned int)i;
}

// Exact global rank = bucket base + (# strictly smaller keys in bucket).
// Keys unique -> permutation -> deterministic. Equal probs order index-asc.
__global__ void k_rank(const unsigned long long* __restrict__ bucketed,
                       const unsigned int* __restrict__ hist,
                       const unsigned int* __restrict__ local,
                       const unsigned int* __restrict__ chunkoff,
                       const float* __restrict__ probs,
                       const float* __restrict__ scal,
                       uint2* __restrict__ ret_rs) {
    int p = blockIdx.x * 256 + threadIdx.x;
    unsigned long long kk = bucketed[p];
    unsigned int b = (unsigned int)(kk >> 31);        // (d<<17)>>31 == d>>14
    unsigned int start = chunkoff[b >> 10] + local[b];
    unsigned int len = hist[b];
    unsigned int c = 0;
    for (unsigned int q = start; q < start + len; ++q)
        c += (bucketed[q] < kk) ? 1u : 0u;
    unsigned int rank = start + c;
    if (rank < NRET) {
        unsigned int i = (unsigned int)(kk & 0x1FFFFu);
        ret_rs[rank] = make_uint2(i, __float_as_uint(probs[i] * scal[2]));
    }
}

// ---------- final gather: temporal batch confinement per XCD ----------
// Batch b is handled entirely by XCD b&7. Each thread owns ONE rank r and
// loops the XCD's 8 batches IN PHASE (software-pipelined, 2 loads in flight):
// at any instant an XCD's live read window is ~1 batch = 2 MiB (+1 MiB write)
// -> fits 4 MiB L2, so the ~2.1x intra-batch line reuse is an L2 hit and L3
// only serves compulsory fills. (R6: all 8 windows live -> 16 MiB -> L2
// thrash -> L3 random-line wall at 1.9 TB/s effective.)
// R4 lesson: randomness stays on the READ side.
__global__ void k_gather(const float4* __restrict__ pts,
                         const uint2* __restrict__ ret_rs,
                         float4* __restrict__ out) {
    int j = blockIdx.x;
    int v = j & 7;                       // XCD
    int s = j >> 3;                      // 0..255 rank-slice slot
    int r = (s << 8) + threadIdx.x;      // rank, same for all 8 batches
    uint2 rs = ret_rs[r];
    float sc = __uint_as_float(rs.y);
    float4 val = pts[(size_t)v * NPTS + rs.x];
    #pragma unroll
    for (int bt = 0; bt < 8; ++bt) {
        int b = v + (bt << 3);
        float4 nxt;
        if (bt < 7) nxt = pts[(size_t)(b + 8) * NPTS + rs.x];
        float4 o;
        o.x = val.x * sc; o.y = val.y * sc; o.z = val.z * sc; o.w = val.w * sc;
        out[(size_t)b * NRET + r] = o;
        val = nxt;
    }
}

extern "C" void kernel_launch(void* const* d_in, const int* in_sizes, int n_in,
                              void* d_out, int out_size, void* d_ws, size_t ws_size,
                              hipStream_t stream) {
    const float* pts = (const float*)d_in[0];   // [64, 131072, 4]
    const float* w   = (const float*)d_in[1];   // [131072]
    float* out = (float*)d_out;

    char* ws = (char*)d_ws;
    unsigned int* hist      = (unsigned int*)(ws + 0);                 // 1 MB
    unsigned int* cnt       = (unsigned int*)(ws + (1 << 20));         // 1 MB
    unsigned int* local     = (unsigned int*)(ws + (2 << 20));         // 1 MB
    unsigned int* chunksum  = (unsigned int*)(ws + (3 << 20));         // 1 KB
    unsigned int* chunkoff  = (unsigned int*)(ws + (3 << 20) + 4096);  // 1 KB
    float*        pmax      = (float*)(ws + (3 << 20) + 8192);         // 1 KB
    float*        scal      = (float*)(ws + (3 << 20) + 12288);        // m, Z, inv
    float*        bs        = (float*)(ws + (3 << 20) + 16384);        // 4 KB
    float*        bs2       = (float*)(ws + (3 << 20) + 24576);        // 4 KB
    float*        probs     = (float*)(ws + (3 << 20) + (1 << 19));    // 512 KB @3.5MB
    unsigned long long* bucketed = (unsigned long long*)(ws + (4 << 20)); // 1 MB
    uint2*        ret_rs    = (uint2*)(ws + (5 << 20));                // 512 KB

    k_zero_pmax     <<<512, 256, 0, stream>>>(w, (uint4*)ws, pmax);
    k_exp_sum       <<<32,  256, 0, stream>>>(w, pmax, probs, bs);   // probs = e
    k_tree          <<<1,  1024, 0, stream>>>(bs, &scal[1]);         // Z
    k_prob_hist_sum <<<32,  256, 0, stream>>>(probs, scal, hist, bs2); // probs = p
    k_scan_local    <<<256, 256, 0, stream>>>(hist, local, chunksum);
    k_scan_chunk_inv<<<1,   256, 0, stream>>>(chunksum, chunkoff, bs2, &scal[2]);
    k_scatter       <<<NPTS / 256, 256, 0, stream>>>(probs, local, chunkoff, cnt, bucketed);
    k_rank          <<<NPTS / 256, 256, 0, stream>>>(bucketed, hist, local, chunkoff,
                                                     probs, scal, ret_rs);
    k_gather        <<<2048, 256, 0, stream>>>((const float4*)pts, ret_rs, (float4*)out);
}